// Round 2
// baseline (194.912 us; speedup 1.0000x reference)
//
#include <hip/hip_runtime.h>
#include <cstddef>
#include <cstdint>

#define BATCH 4
#define SEQ   1024
#define DM    1024
#define NH    16
#define HD    64
#define D3    3072
#define LOG2E 1.44269504088896340736f
#define QSCALE (0.125f * LOG2E)

typedef _Float16 f16x8 __attribute__((ext_vector_type(8)));
typedef _Float16 f16x4 __attribute__((ext_vector_type(4)));
typedef __fp16   h16x2 __attribute__((ext_vector_type(2)));
typedef float    f32x4 __attribute__((ext_vector_type(4)));

#define MFMA16(a, b, c) __builtin_amdgcn_mfma_f32_16x16x32_f16((a), (b), (c), 0, 0, 0)
#define GLD_LDS16(gp, lp) \
  __builtin_amdgcn_global_load_lds((const __attribute__((address_space(1))) unsigned int*)(gp), \
                                   (__attribute__((address_space(3))) unsigned int*)(lp), 16, 0, 0)
#if __has_builtin(__builtin_amdgcn_exp2f)
#define EXP2(x) __builtin_amdgcn_exp2f(x)
#else
#define EXP2(x) exp2f(x)
#endif

// ---------- fused prologue: weight transpose (blocks 0..1023) + x cast
// (1024..3071) + mask pack (3072..). All memory-bound & independent ->
// one launch lets them share the BW shadow instead of running serially.
__global__ __launch_bounds__(256) void prep_all(const float* __restrict__ x,
                                                _Float16* __restrict__ x16,
                                                const int* __restrict__ mask,
                                                unsigned long long* __restrict__ mb,
                                                const float* __restrict__ W1,
                                                _Float16* __restrict__ WT1,
                                                const float* __restrict__ W2,
                                                _Float16* __restrict__ WT2) {
  __shared__ _Float16 T[64 * 72];
  const int tid = threadIdx.x;
  const int bx = blockIdx.x;
  if (bx < 1024) {  // transpose W[K][N] -> WT[N][K], 64x64 tiles
    const int tx = bx & 63, ty = bx >> 6;
    const bool first = tx < 48;
    const float* W = first ? W1 : W2;
    _Float16* WT = first ? WT1 : WT2;
    const int N = first ? D3 : DM;
    const int K = DM;
    const int c0 = (first ? tx : (tx - 48)) * 64;
    const int r0 = ty * 64;
#pragma unroll
    for (int it = 0; it < 4; ++it) {
      const int row = it * 16 + (tid >> 4);
      const int col4 = (tid & 15) * 4;
      float4 wv = *(const float4*)(W + (size_t)(r0 + row) * N + c0 + col4);
      T[(col4 + 0) * 72 + row] = (_Float16)wv.x;
      T[(col4 + 1) * 72 + row] = (_Float16)wv.y;
      T[(col4 + 2) * 72 + row] = (_Float16)wv.z;
      T[(col4 + 3) * 72 + row] = (_Float16)wv.w;
    }
    __syncthreads();
#pragma unroll
    for (int it = 0; it < 2; ++it) {
      const int g = it * 256 + tid;
      const int col = g >> 3, seg = g & 7;
      *(f16x8*)(WT + (size_t)(c0 + col) * K + r0 + seg * 8) =
          *(const f16x8*)(T + col * 72 + seg * 8);
    }
  } else if (bx < 3072) {  // fp32 -> fp16 cast of x
    const int i = (bx - 1024) * 256 + tid;
    float4 a = ((const float4*)x)[i * 2];
    float4 b = ((const float4*)x)[i * 2 + 1];
    f16x8 o;
    o[0] = (_Float16)a.x; o[1] = (_Float16)a.y; o[2] = (_Float16)a.z; o[3] = (_Float16)a.w;
    o[4] = (_Float16)b.x; o[5] = (_Float16)b.y; o[6] = (_Float16)b.z; o[7] = (_Float16)b.w;
    ((f16x8*)x16)[i] = o;
  } else {  // mask -> bitmask
    const size_t i = (size_t)(bx - 3072) * 256 + tid;
    const int m = mask[i];
    unsigned long long bits = __ballot(m != 0);
    if ((tid & 63) == 0) mb[i >> 6] = bits;
  }
}

// ---------- GEMM: C[M][N] = A * BT^T + bias. BK=64, XOR-swizzled LDS ----------
// O-projection: TN=128 (32 MFMA per barrier-drain, 256 blocks = 1/CU).
template <typename OutT, bool QKV, int TN>
__global__ __launch_bounds__(256) void gemm_bt(const _Float16* __restrict__ A,
                                               const _Float16* __restrict__ BT,
                                               const float* __restrict__ bias,
                                               OutT* __restrict__ C,
                                               _Float16* __restrict__ vTp,
                                               int M, int N, int K) {
  constexpr int NT = TN / 32;  // n-frags per wave
  __shared__ _Float16 As[128 * 64];
  __shared__ _Float16 Bs[TN * 64];
  const int tid = threadIdx.x;
  const int l15 = tid & 15;
  const int quad = (tid & 63) >> 4;
  const int w = tid >> 6;
  const int wm = w >> 1, wn = w & 1;
  const int rowbase = blockIdx.y * 128;
  const int colbase = blockIdx.x * TN;

  f32x4 acc[4][NT];
#pragma unroll
  for (int mt = 0; mt < 4; ++mt)
#pragma unroll
    for (int nt = 0; nt < NT; ++nt) acc[mt][nt] = (f32x4){0.f, 0.f, 0.f, 0.f};

  for (int k0 = 0; k0 < K; k0 += 64) {
    __syncthreads();  // readers of prev tile done
#pragma unroll
    for (int it = 0; it < 4; ++it) {
      const int g = it * 256 + tid;
      const int r = g >> 3, cs = (g & 7) ^ (r & 7);
      GLD_LDS16(A + (size_t)(rowbase + r) * K + k0 + cs * 8, As + g * 8);
    }
#pragma unroll
    for (int it = 0; it < TN / 32; ++it) {
      const int g = it * 256 + tid;
      const int r = g >> 3, cs = (g & 7) ^ (r & 7);
      GLD_LDS16(BT + (size_t)(colbase + r) * K + k0 + cs * 8, Bs + g * 8);
    }
    __syncthreads();  // DMA writes visible (compiler drains vmcnt)
#pragma unroll
    for (int kh = 0; kh < 2; ++kh) {
      f16x8 a[4], b[NT];
#pragma unroll
      for (int mt = 0; mt < 4; ++mt) {
        const int row = wm * 64 + mt * 16 + l15;
        a[mt] = *(const f16x8*)(As + row * 64 + (((kh * 4 + quad) ^ (row & 7)) << 3));
      }
#pragma unroll
      for (int nt = 0; nt < NT; ++nt) {
        const int row = wn * (TN / 2) + nt * 16 + l15;
        b[nt] = *(const f16x8*)(Bs + row * 64 + (((kh * 4 + quad) ^ (row & 7)) << 3));
      }
#pragma unroll
      for (int mt = 0; mt < 4; ++mt)
#pragma unroll
        for (int nt = 0; nt < NT; ++nt)
          acc[mt][nt] = MFMA16(a[mt], b[nt], acc[mt][nt]);
    }
  }

  float bv[NT];
#pragma unroll
  for (int nt = 0; nt < NT; ++nt) bv[nt] = bias[colbase + wn * (TN / 2) + nt * 16 + l15];
#pragma unroll
  for (int mt = 0; mt < 4; ++mt)
#pragma unroll
    for (int nt = 0; nt < NT; ++nt) {
      const int col = colbase + wn * (TN / 2) + nt * 16 + l15;
      if (QKV) {
        const int reg3 = (col >> 6) % 3;  // wave-uniform
        if (reg3 == 2) {
          const int hh = col / 192;
          const int d = col - hh * 192 - 128;
          const int row0 = rowbase + wm * 64 + mt * 16 + quad * 4;
          const int bb = row0 >> 10, s0 = row0 & 1023;
          f16x4 pk;
#pragma unroll
          for (int r = 0; r < 4; ++r) pk[r] = (_Float16)(acc[mt][nt][r] + bv[nt]);
          *(f16x4*)(vTp + ((size_t)((bb * NH + hh) * HD + d)) * SEQ + s0) = pk;
        } else {
          const float sc = (reg3 == 0) ? QSCALE : 1.f;
#pragma unroll
          for (int r = 0; r < 4; ++r) {
            const int row = rowbase + wm * 64 + mt * 16 + quad * 4 + r;
            C[(size_t)row * N + col] = (OutT)((acc[mt][nt][r] + bv[nt]) * sc);
          }
        }
      } else {
#pragma unroll
        for (int r = 0; r < 4; ++r) {
          const int row = rowbase + wm * 64 + mt * 16 + quad * 4 + r;
          C[(size_t)row * N + col] = (OutT)(acc[mt][nt][r] + bv[nt]);
        }
      }
    }
}

// ---------- QKV GEMM: 256x256 tile, 8-wave, 8-phase counted-vmcnt schedule ----------
// Tiles split into K-halves (kk0/kk1); tile t lives in buffer t&1.
// Steady-state stage map (iteration computes T=2i from buf0 ph1-4, T+1 from buf1 ph5-8):
//   ph1: (T+1)A-kk1   ph2: (T+1)B-kk1   ph3: (T+2)A-kk0   ph4: (T+2)B-kk0
//   ph5: (T+2)A-kk1   ph6: (T+2)B-kk1   ph7: (T+3)A-kk0   ph8: (T+3)B-kk0
// vmcnt(8) before the end-barrier of even phases leaves the 4 newest halves in
// flight; everything read 1-2 phases later has landed. Peeled tail: 8 -> 4 -> 0.
#define BAR() asm volatile("s_barrier" ::: "memory")
#define WVM(N) asm volatile("s_waitcnt vmcnt(" #N ")" ::: "memory")

// frag addr within a 16KB K-half region: row-pair major, 8 slots/pair, XOR swizzle.
// slot(r,c) = (r>>1)*8 + ((((r&1)<<2)|c) ^ ((r>>1)&7))  -> 2-way (free) on ds_read_b128.
#define LDAF(BUF, KK)                                                           \
  _Pragma("unroll") for (int mt = 0; mt < 8; ++mt) {                            \
    const int rr = wm * 128 + mt * 16 + l15;                                    \
    const int idx = ((rr >> 1) << 3) |                                          \
                    ((((rr & 1) << 2) | quad) ^ ((rr >> 1) & 7));               \
    af[mt] = *(const f16x8*)(&LA[BUF][(KK) * 8192 + idx * 8]);                  \
  }

#define LDBF(BUF, KK, NQ)                                                       \
  _Pragma("unroll") for (int t = 0; t < 2; ++t) {                               \
    const int rr = wn * 64 + (NQ) * 32 + t * 16 + l15;                          \
    const int idx = ((rr >> 1) << 3) |                                          \
                    ((((rr & 1) << 2) | quad) ^ ((rr >> 1) & 7));               \
    bf[t] = *(const f16x8*)(&LB[BUF][(KK) * 8192 + idx * 8]);                   \
  }

#define MFMAQ(NQ)                                                               \
  __builtin_amdgcn_s_setprio(1);                                                \
  _Pragma("unroll") for (int mt = 0; mt < 8; ++mt) {                            \
    acc[mt][(NQ) * 2 + 0] = MFMA16(af[mt], bf[0], acc[mt][(NQ) * 2 + 0]);       \
    acc[mt][(NQ) * 2 + 1] = MFMA16(af[mt], bf[1], acc[mt][(NQ) * 2 + 1]);       \
  }                                                                             \
  __builtin_amdgcn_s_setprio(0);

__global__ __launch_bounds__(512, 2) void gemm_qkv8(const _Float16* __restrict__ A,
                                                    const _Float16* __restrict__ BT,
                                                    const float* __restrict__ bias,
                                                    _Float16* __restrict__ C,
                                                    _Float16* __restrict__ vTp) {
  __shared__ __align__(16) _Float16 LA[2][2 * 8192];  // [buf][kk-half 16KB each]
  __shared__ __align__(16) _Float16 LB[2][2 * 8192];  // 128 KiB total
  const int tid = threadIdx.x;
  const int l15 = tid & 15, quad = (tid & 63) >> 4, w = tid >> 6;
  const int wm = w >> 2, wn = w & 3;  // 2M x 4N waves; wave output 128x64
  const int rowbase = blockIdx.y * 256, colbase = blockIdx.x * 256;

  f32x4 acc[8][4];
#pragma unroll
  for (int mt = 0; mt < 8; ++mt)
#pragma unroll
    for (int nt = 0; nt < 4; ++nt) acc[mt][nt] = (f32x4){0.f, 0.f, 0.f, 0.f};

  // stage one K-half (256 rows x 32 cols): linear LDS dest (gload_lds constraint),
  // inverse-swizzled GLOBAL source (m173 pattern). 2 insts/thread = 2 vmcnt units/wave.
  auto stage = [&](const _Float16* __restrict__ G, int tb, int kt, int h,
                   _Float16* Lr) {
#pragma unroll
    for (int it2 = 0; it2 < 2; ++it2) {
      const int g = it2 * 512 + tid;
      const int pr = g >> 3, s = g & 7;
      const int inv = s ^ (pr & 7);
      const int r2 = (pr << 1) | (inv >> 2), c = inv & 3;
      GLD_LDS16(G + (size_t)(tb + r2) * DM + (kt << 6) + (h << 5) + (c << 3),
                Lr + g * 8);
    }
  };

  // prologue: t0 all 4 halves + t1 kk0 halves (12 insts); land t0-kk0 (oldest 4)
  stage(A, rowbase, 0, 0, &LA[0][0]);
  stage(BT, colbase, 0, 0, &LB[0][0]);
  stage(A, rowbase, 0, 1, &LA[0][8192]);
  stage(BT, colbase, 0, 1, &LB[0][8192]);
  stage(A, rowbase, 1, 0, &LA[1][0]);
  stage(BT, colbase, 1, 0, &LB[1][0]);
  WVM(8);
  BAR();

#pragma unroll 1
  for (int it = 0; it < 7; ++it) {
    const int t1 = 2 * it + 1, t2 = 2 * it + 2, t3 = 2 * it + 3;
    f16x8 af[8], bf[2];
    // ph1: buf0 (kk0,nq0)
    LDAF(0, 0) LDBF(0, 0, 0) stage(A, rowbase, t1, 1, &LA[1][8192]);
    BAR(); MFMAQ(0) BAR();
    // ph2: buf0 (kk0,nq1)
    LDBF(0, 0, 1) stage(BT, colbase, t1, 1, &LB[1][8192]);
    BAR(); MFMAQ(1) WVM(8); BAR();
    // ph3: buf0 (kk1,nq0)
    LDAF(0, 1) LDBF(0, 1, 0) stage(A, rowbase, t2, 0, &LA[0][0]);
    BAR(); MFMAQ(0) BAR();
    // ph4: buf0 (kk1,nq1)
    LDBF(0, 1, 1) stage(BT, colbase, t2, 0, &LB[0][0]);
    BAR(); MFMAQ(1) WVM(8); BAR();
    // ph5: buf1 (kk0,nq0)
    LDAF(1, 0) LDBF(1, 0, 0) stage(A, rowbase, t2, 1, &LA[0][8192]);
    BAR(); MFMAQ(0) BAR();
    // ph6: buf1 (kk0,nq1)
    LDBF(1, 0, 1) stage(BT, colbase, t2, 1, &LB[0][8192]);
    BAR(); MFMAQ(1) WVM(8); BAR();
    // ph7: buf1 (kk1,nq0)
    LDAF(1, 1) LDBF(1, 1, 0) stage(A, rowbase, t3, 0, &LA[1][0]);
    BAR(); MFMAQ(0) BAR();
    // ph8: buf1 (kk1,nq1)
    LDBF(1, 1, 1) stage(BT, colbase, t3, 0, &LB[1][0]);
    BAR(); MFMAQ(1) WVM(8); BAR();
  }
  {  // tail: tiles 14,15; only t15-kk1 remains to stage; waits shrink 8->4->0
    f16x8 af[8], bf[2];
    LDAF(0, 0) LDBF(0, 0, 0) stage(A, rowbase, 15, 1, &LA[1][8192]);
    BAR(); MFMAQ(0) BAR();
    LDBF(0, 0, 1) stage(BT, colbase, 15, 1, &LB[1][8192]);
    BAR(); MFMAQ(1) WVM(8); BAR();
    LDAF(0, 1) LDBF(0, 1, 0)
    BAR(); MFMAQ(0) BAR();
    LDBF(0, 1, 1)
    BAR(); MFMAQ(1) WVM(4); BAR();
    LDAF(1, 0) LDBF(1, 0, 0)
    BAR(); MFMAQ(0) BAR();
    LDBF(1, 0, 1)
    BAR(); MFMAQ(1) WVM(0); BAR();
    LDAF(1, 1) LDBF(1, 1, 0)
    BAR(); MFMAQ(0) BAR();
    LDBF(1, 1, 1)
    BAR(); MFMAQ(1) BAR();
  }

  // epilogue: each wave's 64 output cols lie in ONE 64-col block -> reg3 wave-uniform
  float bv[4];
#pragma unroll
  for (int nt = 0; nt < 4; ++nt) bv[nt] = bias[colbase + wn * 64 + nt * 16 + l15];
  const int cb6 = (colbase >> 6) + wn;
  const int r3 = cb6 % 3;
  if (r3 == 2) {  // v columns -> vT[d][s]
    const int hh = cb6 / 3;
#pragma unroll
    for (int mt = 0; mt < 8; ++mt) {
      const int row0 = rowbase + wm * 128 + mt * 16 + quad * 4;
      const int bb = row0 >> 10, s0 = row0 & 1023;
#pragma unroll
      for (int nt = 0; nt < 4; ++nt) {
        const int d = colbase + wn * 64 + nt * 16 + l15 - hh * 192 - 128;
        f16x4 pk;
#pragma unroll
        for (int r = 0; r < 4; ++r) pk[r] = (_Float16)(acc[mt][nt][r] + bv[nt]);
        *(f16x4*)(vTp + ((size_t)((bb * NH + hh) * HD + d)) * SEQ + s0) = pk;
      }
    }
  } else {
    const float sc = (r3 == 0) ? QSCALE : 1.f;  // q: fold 1/8 * log2(e)
#pragma unroll
    for (int mt = 0; mt < 8; ++mt) {
      const int row0 = rowbase + wm * 128 + mt * 16 + quad * 4;
#pragma unroll
      for (int nt = 0; nt < 4; ++nt) {
        const int col = colbase + wn * 64 + nt * 16 + l15;
#pragma unroll
        for (int r = 0; r < 4; ++r)
          C[(size_t)(row0 + r) * D3 + col] = (_Float16)((acc[mt][nt][r] + bv[nt]) * sc);
      }
    }
  }
}

// ---------- MFMA flash attention v3 + XCD swizzle ----------
// 1D grid 512: i = outer*64 + qtile*8 + xcd; blocks sharing (b,h) keep i%8
// constant -> same XCD -> K/V L2 reuse (2MB/XCD < 4MB L2).
__global__ __launch_bounds__(256) void attn(const _Float16* __restrict__ qkv,
                                            const _Float16* __restrict__ vT,
                                            const unsigned long long* __restrict__ mb,
                                            _Float16* __restrict__ vals) {
  __shared__ _Float16 Ks[64 * 72];
  __shared__ _Float16 Vt[64 * 72];       // Vt[d][sk]
  __shared__ _Float16 Ps[4][32 * 72];    // per-wave P [32 q][64 k]
  __shared__ __align__(8) _Float16 LUT[16][4];
  const int tid = threadIdx.x;
  const int l15 = tid & 15, quad = (tid & 63) >> 4, w = tid >> 6;
  const int i = blockIdx.x;
  const int bh = (i >> 6) * 8 + (i & 7);
  const int b = bh >> 4, h = bh & 15;
  const int q0 = ((i >> 3) & 7) << 7;    // 128-row q tile

  if (tid < 16) {
    LUT[tid][0] = (tid & 1) ? (_Float16)1.f : (_Float16)0.f;
    LUT[tid][1] = (tid & 2) ? (_Float16)1.f : (_Float16)0.f;
    LUT[tid][2] = (tid & 4) ? (_Float16)1.f : (_Float16)0.f;
    LUT[tid][3] = (tid & 8) ? (_Float16)1.f : (_Float16)0.f;
  }

  const _Float16* qb = qkv + (size_t)b * SEQ * D3 + h * 192;
  f16x8 qf[2][2];
#pragma unroll
  for (int qn = 0; qn < 2; ++qn)
#pragma unroll
    for (int hf = 0; hf < 2; ++hf)
      qf[qn][hf] = *(const f16x8*)(qb + (size_t)(q0 + w * 32 + qn * 16 + l15) * D3 +
                                   hf * 32 + quad * 8);

  const _Float16* kg = qb + 64;
  const _Float16* vg = vT + (size_t)((b * NH + h) * HD) * SEQ;
  const int sr = tid >> 3, sseg = tid & 7;  // K staging: rows sr, sr+32
  const int vd = tid >> 2, vs = tid & 3;    // V staging: row vd, segs vs, vs+4
  const size_t mb0 = (size_t)(b * SEQ + q0 + w * 32 + l15) * 16;
  const size_t mb1 = (size_t)(b * SEQ + q0 + w * 32 + 16 + l15) * 16;

  f16x8 k0r = *(const f16x8*)(kg + (size_t)sr * D3 + sseg * 8);
  f16x8 k1r = *(const f16x8*)(kg + (size_t)(sr + 32) * D3 + sseg * 8);
  f16x8 v0r = *(const f16x8*)(vg + (size_t)vd * SEQ + vs * 8);
  f16x8 v1r = *(const f16x8*)(vg + (size_t)vd * SEQ + 32 + vs * 8);
  unsigned long long mr0 = mb[mb0], mr1 = mb[mb1];

  f32x4 lacc[2];
  f32x4 o_[2][4];
#pragma unroll
  for (int qn = 0; qn < 2; ++qn) {
    lacc[qn] = (f32x4){0.f, 0.f, 0.f, 0.f};
#pragma unroll
    for (int dt = 0; dt < 4; ++dt) o_[qn][dt] = (f32x4){0.f, 0.f, 0.f, 0.f};
  }
  f16x8 ones;
#pragma unroll
  for (int i2 = 0; i2 < 8; ++i2) ones[i2] = (_Float16)1.f;

  for (int kt = 0; kt < 16; ++kt) {
    if (kt) __syncthreads();  // prev iter done reading Ks/Vt
    *(f16x8*)(Ks + sr * 72 + sseg * 8) = k0r;
    *(f16x8*)(Ks + (sr + 32) * 72 + sseg * 8) = k1r;
    *(f16x8*)(Vt + vd * 72 + vs * 8) = v0r;
    *(f16x8*)(Vt + vd * 72 + 32 + vs * 8) = v1r;
    __syncthreads();  // also makes LUT visible before first use
    const unsigned long long mc[2] = {mr0, mr1};
    if (kt < 15) {  // prefetch next tile into regs during compute
      const int kn = (kt + 1) << 6;
      k0r = *(const f16x8*)(kg + (size_t)(kn + sr) * D3 + sseg * 8);
      k1r = *(const f16x8*)(kg + (size_t)(kn + sr + 32) * D3 + sseg * 8);
      v0r = *(const f16x8*)(vg + (size_t)vd * SEQ + kn + vs * 8);
      v1r = *(const f16x8*)(vg + (size_t)vd * SEQ + kn + 32 + vs * 8);
      mr0 = mb[mb0 + kt + 1];
      mr1 = mb[mb1 + kt + 1];
    }
    // S^T = K Q^T (log2-domain scores): col=l15=q, rows mt*16+quad*4+r = k
    f32x4 st[4][2];
#pragma unroll
    for (int mt = 0; mt < 4; ++mt)
#pragma unroll
      for (int qn = 0; qn < 2; ++qn) st[mt][qn] = (f32x4){0.f, 0.f, 0.f, 0.f};
#pragma unroll
    for (int mt = 0; mt < 4; ++mt) {
      f16x8 ka0 = *(const f16x8*)(Ks + (mt * 16 + l15) * 72 + quad * 8);
      f16x8 ka1 = *(const f16x8*)(Ks + (mt * 16 + l15) * 72 + 32 + quad * 8);
#pragma unroll
      for (int qn = 0; qn < 2; ++qn) {
        st[mt][qn] = MFMA16(ka0, qf[qn][0], st[mt][qn]);
        st[mt][qn] = MFMA16(ka1, qf[qn][1], st[mt][qn]);
      }
    }
    // exp2 (no max subtraction) + mask-LUT multiply + store P
#pragma unroll
    for (int qn = 0; qn < 2; ++qn)
#pragma unroll
      for (int mt = 0; mt < 4; ++mt) {
        float e0 = EXP2(fminf(st[mt][qn][0], 15.f));
        float e1 = EXP2(fminf(st[mt][qn][1], 15.f));
        float e2 = EXP2(fminf(st[mt][qn][2], 15.f));
        float e3 = EXP2(fminf(st[mt][qn][3], 15.f));
        h16x2 lo = __builtin_amdgcn_cvt_pkrtz(e0, e1);
        h16x2 hi = __builtin_amdgcn_cvt_pkrtz(e2, e3);
        f16x4 pk;
        pk[0] = (_Float16)lo[0]; pk[1] = (_Float16)lo[1];
        pk[2] = (_Float16)hi[0]; pk[3] = (_Float16)hi[1];
        const unsigned nib = (unsigned)(mc[qn] >> (mt * 16 + quad * 4)) & 15u;
        pk *= *(const f16x4*)LUT[nib];
        *(f16x4*)(&Ps[w][(qn * 16 + l15) * 72 + mt * 16 + quad * 4]) = pk;
      }
    // O += P V ; l += P·1  (wave-private P; V frags shared across q-frags)
    f16x8 pa[2][2];
#pragma unroll
    for (int qn = 0; qn < 2; ++qn) {
      pa[qn][0] = *(const f16x8*)(&Ps[w][(qn * 16 + l15) * 72 + quad * 8]);
      pa[qn][1] = *(const f16x8*)(&Ps[w][(qn * 16 + l15) * 72 + 32 + quad * 8]);
      lacc[qn] = MFMA16(pa[qn][0], ones, lacc[qn]);
      lacc[qn] = MFMA16(pa[qn][1], ones, lacc[qn]);
    }
#pragma unroll
    for (int dt = 0; dt < 4; ++dt) {
      f16x8 vb0 = *(const f16x8*)(Vt + (dt * 16 + l15) * 72 + quad * 8);
      f16x8 vb1 = *(const f16x8*)(Vt + (dt * 16 + l15) * 72 + 32 + quad * 8);
#pragma unroll
      for (int qn = 0; qn < 2; ++qn) {
        o_[qn][dt] = MFMA16(pa[qn][0], vb0, o_[qn][dt]);
        o_[qn][dt] = MFMA16(pa[qn][1], vb1, o_[qn][dt]);
      }
    }
  }
  // normalize + write: lacc rows align with o_ rows -> no shuffles
#pragma unroll
  for (int qn = 0; qn < 2; ++qn) {
    f32x4 inv;
#pragma unroll
    for (int r = 0; r < 4; ++r) inv[r] = 1.f / lacc[qn][r];
#pragma unroll
    for (int dt = 0; dt < 4; ++dt)
#pragma unroll
      for (int r = 0; r < 4; ++r)
        vals[(size_t)(b * SEQ + q0 + w * 32 + qn * 16 + quad * 4 + r) * DM +
             h * HD + dt * 16 + l15] = (_Float16)(o_[qn][dt][r] * inv[r]);
  }
}

extern "C" void kernel_launch(void* const* d_in, const int* in_sizes, int n_in,
                              void* d_out, int out_size, void* d_ws, size_t ws_size,
                              hipStream_t stream) {
  const float* x    = (const float*)d_in[0];
  const int*   mask = (const int*)  d_in[1];
  const float* Wqkv = (const float*)d_in[2];
  const float* bqkv = (const float*)d_in[3];
  const float* Wo   = (const float*)d_in[4];
  const float* bo   = (const float*)d_in[5];
  float* out = (float*)d_out;

  char* ws = (char*)d_ws;
  _Float16* qkv16  = (_Float16*)ws;                    ws += (size_t)BATCH*SEQ*D3*2;   // 24MB (v-cols unused)
  _Float16* vT16   = (_Float16*)ws;                    ws += (size_t)BATCH*DM*SEQ*2;   //  8MB
  _Float16* x16    = (_Float16*)ws;                    ws += (size_t)BATCH*SEQ*DM*2;   //  8MB
  _Float16* WqkvT  = (_Float16*)ws;                    ws += (size_t)DM*D3*2;          //  6MB
  _Float16* WoT    = (_Float16*)ws;                    ws += (size_t)DM*DM*2;          //  2MB
  _Float16* vals16 = (_Float16*)ws;                    ws += (size_t)BATCH*SEQ*DM*2;   //  8MB
  unsigned long long* mbits = (unsigned long long*)ws;                                 // 0.5MB

  // transpose blocks first (they feed the GEMM B operand), then cast, then mask
  prep_all<<<3072 + (BATCH*SEQ*SEQ)/256, 256, 0, stream>>>(
      x, x16, mask, mbits, Wqkv, WqkvT, Wo, WoT);

  gemm_qkv8<<<dim3(D3/256, BATCH*SEQ/256), 512, 0, stream>>>(
      x16, WqkvT, bqkv, qkv16, vT16);
  attn<<<512, 256, 0, stream>>>(qkv16, vT16, mbits, vals16);
  gemm_bt<float, false, 128><<<dim3(DM/128, (BATCH*SEQ)/128), 256, 0, stream>>>(
      vals16, WoT, bo, out, nullptr, BATCH*SEQ, DM, DM);
}

// Round 3
// 190.128 us; speedup vs baseline: 1.0252x; 1.0252x over previous
//
#include <hip/hip_runtime.h>
#include <cstddef>
#include <cstdint>

#define BATCH 4
#define SEQ   1024
#define DM    1024
#define NH    16
#define HD    64
#define D3    3072
#define LOG2E 1.44269504088896340736f
#define QSCALE (0.125f * LOG2E)

typedef _Float16 f16x8 __attribute__((ext_vector_type(8)));
typedef _Float16 f16x4 __attribute__((ext_vector_type(4)));
typedef __fp16   h16x2 __attribute__((ext_vector_type(2)));
typedef float    f32x4 __attribute__((ext_vector_type(4)));

#define MFMA16(a, b, c) __builtin_amdgcn_mfma_f32_16x16x32_f16((a), (b), (c), 0, 0, 0)
#define GLD_LDS16(gp, lp) \
  __builtin_amdgcn_global_load_lds((const __attribute__((address_space(1))) unsigned int*)(gp), \
                                   (__attribute__((address_space(3))) unsigned int*)(lp), 16, 0, 0)
#if __has_builtin(__builtin_amdgcn_exp2f)
#define EXP2(x) __builtin_amdgcn_exp2f(x)
#else
#define EXP2(x) exp2f(x)
#endif

// ---------- fused prologue: weight transpose (blocks 0..1023) + x cast
// (1024..3071) + mask pack (3072..). All memory-bound & independent ->
// one launch lets them share the BW shadow instead of running serially.
__global__ __launch_bounds__(256) void prep_all(const float* __restrict__ x,
                                                _Float16* __restrict__ x16,
                                                const int* __restrict__ mask,
                                                unsigned long long* __restrict__ mb,
                                                const float* __restrict__ W1,
                                                _Float16* __restrict__ WT1,
                                                const float* __restrict__ W2,
                                                _Float16* __restrict__ WT2) {
  __shared__ _Float16 T[64 * 72];
  const int tid = threadIdx.x;
  const int bx = blockIdx.x;
  if (bx < 1024) {  // transpose W[K][N] -> WT[N][K], 64x64 tiles
    const int tx = bx & 63, ty = bx >> 6;
    const bool first = tx < 48;
    const float* W = first ? W1 : W2;
    _Float16* WT = first ? WT1 : WT2;
    const int N = first ? D3 : DM;
    const int K = DM;
    const int c0 = (first ? tx : (tx - 48)) * 64;
    const int r0 = ty * 64;
#pragma unroll
    for (int it = 0; it < 4; ++it) {
      const int row = it * 16 + (tid >> 4);
      const int col4 = (tid & 15) * 4;
      float4 wv = *(const float4*)(W + (size_t)(r0 + row) * N + c0 + col4);
      T[(col4 + 0) * 72 + row] = (_Float16)wv.x;
      T[(col4 + 1) * 72 + row] = (_Float16)wv.y;
      T[(col4 + 2) * 72 + row] = (_Float16)wv.z;
      T[(col4 + 3) * 72 + row] = (_Float16)wv.w;
    }
    __syncthreads();
#pragma unroll
    for (int it = 0; it < 2; ++it) {
      const int g = it * 256 + tid;
      const int col = g >> 3, seg = g & 7;
      *(f16x8*)(WT + (size_t)(c0 + col) * K + r0 + seg * 8) =
          *(const f16x8*)(T + col * 72 + seg * 8);
    }
  } else if (bx < 3072) {  // fp32 -> fp16 cast of x
    const int i = (bx - 1024) * 256 + tid;
    float4 a = ((const float4*)x)[i * 2];
    float4 b = ((const float4*)x)[i * 2 + 1];
    f16x8 o;
    o[0] = (_Float16)a.x; o[1] = (_Float16)a.y; o[2] = (_Float16)a.z; o[3] = (_Float16)a.w;
    o[4] = (_Float16)b.x; o[5] = (_Float16)b.y; o[6] = (_Float16)b.z; o[7] = (_Float16)b.w;
    ((f16x8*)x16)[i] = o;
  } else {  // mask -> bitmask
    const size_t i = (size_t)(bx - 3072) * 256 + tid;
    const int m = mask[i];
    unsigned long long bits = __ballot(m != 0);
    if ((tid & 63) == 0) mb[i >> 6] = bits;
  }
}

// ---------- GEMM: C[M][N] = A * BT^T + bias. BK=64, XOR-swizzled LDS ----------
// 2-barrier m97 structure. Relies on >=2 blocks/CU for cross-block overlap of
// the vmcnt(0)+barrier drain (m114): QKV TN=128 -> 768 blocks (~3/CU),
// O-proj TN=64 -> 512 blocks (2/CU). Do NOT grow tiles to 1 block/CU here.
template <typename OutT, bool QKV, int TN>
__global__ __launch_bounds__(256) void gemm_bt(const _Float16* __restrict__ A,
                                               const _Float16* __restrict__ BT,
                                               const float* __restrict__ bias,
                                               OutT* __restrict__ C,
                                               _Float16* __restrict__ vTp,
                                               int M, int N, int K) {
  constexpr int NT = TN / 32;  // n-frags per wave
  __shared__ _Float16 As[128 * 64];
  __shared__ _Float16 Bs[TN * 64];
  const int tid = threadIdx.x;
  const int l15 = tid & 15;
  const int quad = (tid & 63) >> 4;
  const int w = tid >> 6;
  const int wm = w >> 1, wn = w & 1;
  const int rowbase = blockIdx.y * 128;
  const int colbase = blockIdx.x * TN;

  f32x4 acc[4][NT];
#pragma unroll
  for (int mt = 0; mt < 4; ++mt)
#pragma unroll
    for (int nt = 0; nt < NT; ++nt) acc[mt][nt] = (f32x4){0.f, 0.f, 0.f, 0.f};

  for (int k0 = 0; k0 < K; k0 += 64) {
    __syncthreads();  // readers of prev tile done
#pragma unroll
    for (int it = 0; it < 4; ++it) {
      const int g = it * 256 + tid;
      const int r = g >> 3, cs = (g & 7) ^ (r & 7);
      GLD_LDS16(A + (size_t)(rowbase + r) * K + k0 + cs * 8, As + g * 8);
    }
#pragma unroll
    for (int it = 0; it < TN / 32; ++it) {
      const int g = it * 256 + tid;
      const int r = g >> 3, cs = (g & 7) ^ (r & 7);
      GLD_LDS16(BT + (size_t)(colbase + r) * K + k0 + cs * 8, Bs + g * 8);
    }
    __syncthreads();  // DMA writes visible (compiler drains vmcnt)
#pragma unroll
    for (int kh = 0; kh < 2; ++kh) {
      f16x8 a[4], b[NT];
#pragma unroll
      for (int mt = 0; mt < 4; ++mt) {
        const int row = wm * 64 + mt * 16 + l15;
        a[mt] = *(const f16x8*)(As + row * 64 + (((kh * 4 + quad) ^ (row & 7)) << 3));
      }
#pragma unroll
      for (int nt = 0; nt < NT; ++nt) {
        const int row = wn * (TN / 2) + nt * 16 + l15;
        b[nt] = *(const f16x8*)(Bs + row * 64 + (((kh * 4 + quad) ^ (row & 7)) << 3));
      }
#pragma unroll
      for (int mt = 0; mt < 4; ++mt)
#pragma unroll
        for (int nt = 0; nt < NT; ++nt)
          acc[mt][nt] = MFMA16(a[mt], b[nt], acc[mt][nt]);
    }
  }

  float bv[NT];
#pragma unroll
  for (int nt = 0; nt < NT; ++nt) bv[nt] = bias[colbase + wn * (TN / 2) + nt * 16 + l15];
#pragma unroll
  for (int mt = 0; mt < 4; ++mt)
#pragma unroll
    for (int nt = 0; nt < NT; ++nt) {
      const int col = colbase + wn * (TN / 2) + nt * 16 + l15;
      if (QKV) {
        const int reg3 = (col >> 6) % 3;  // wave-uniform
        if (reg3 == 2) {
          const int hh = col / 192;
          const int d = col - hh * 192 - 128;
          const int row0 = rowbase + wm * 64 + mt * 16 + quad * 4;
          const int bb = row0 >> 10, s0 = row0 & 1023;
          f16x4 pk;
#pragma unroll
          for (int r = 0; r < 4; ++r) pk[r] = (_Float16)(acc[mt][nt][r] + bv[nt]);
          *(f16x4*)(vTp + ((size_t)((bb * NH + hh) * HD + d)) * SEQ + s0) = pk;
        } else {
          const float sc = (reg3 == 0) ? QSCALE : 1.f;  // q: fold 1/8 * log2(e)
#pragma unroll
          for (int r = 0; r < 4; ++r) {
            const int row = rowbase + wm * 64 + mt * 16 + quad * 4 + r;
            C[(size_t)row * N + col] = (OutT)((acc[mt][nt][r] + bv[nt]) * sc);
          }
        }
      } else {
#pragma unroll
        for (int r = 0; r < 4; ++r) {
          const int row = rowbase + wm * 64 + mt * 16 + quad * 4 + r;
          C[(size_t)row * N + col] = (OutT)(acc[mt][nt][r] + bv[nt]);
        }
      }
    }
}

// ---------- MFMA flash attention v3 + XCD swizzle ----------
// 1D grid 512: i = outer*64 + qtile*8 + xcd; blocks sharing (b,h) keep i%8
// constant -> same XCD -> K/V L2 reuse (2MB/XCD < 4MB L2).
__global__ __launch_bounds__(256) void attn(const _Float16* __restrict__ qkv,
                                            const _Float16* __restrict__ vT,
                                            const unsigned long long* __restrict__ mb,
                                            _Float16* __restrict__ vals) {
  __shared__ _Float16 Ks[64 * 72];
  __shared__ _Float16 Vt[64 * 72];       // Vt[d][sk]
  __shared__ _Float16 Ps[4][32 * 72];    // per-wave P [32 q][64 k]
  __shared__ __align__(8) _Float16 LUT[16][4];
  const int tid = threadIdx.x;
  const int l15 = tid & 15, quad = (tid & 63) >> 4, w = tid >> 6;
  const int i = blockIdx.x;
  const int bh = (i >> 6) * 8 + (i & 7);
  const int b = bh >> 4, h = bh & 15;
  const int q0 = ((i >> 3) & 7) << 7;    // 128-row q tile

  if (tid < 16) {
    LUT[tid][0] = (tid & 1) ? (_Float16)1.f : (_Float16)0.f;
    LUT[tid][1] = (tid & 2) ? (_Float16)1.f : (_Float16)0.f;
    LUT[tid][2] = (tid & 4) ? (_Float16)1.f : (_Float16)0.f;
    LUT[tid][3] = (tid & 8) ? (_Float16)1.f : (_Float16)0.f;
  }

  const _Float16* qb = qkv + (size_t)b * SEQ * D3 + h * 192;
  f16x8 qf[2][2];
#pragma unroll
  for (int qn = 0; qn < 2; ++qn)
#pragma unroll
    for (int hf = 0; hf < 2; ++hf)
      qf[qn][hf] = *(const f16x8*)(qb + (size_t)(q0 + w * 32 + qn * 16 + l15) * D3 +
                                   hf * 32 + quad * 8);

  const _Float16* kg = qb + 64;
  const _Float16* vg = vT + (size_t)((b * NH + h) * HD) * SEQ;
  const int sr = tid >> 3, sseg = tid & 7;  // K staging: rows sr, sr+32
  const int vd = tid >> 2, vs = tid & 3;    // V staging: row vd, segs vs, vs+4
  const size_t mb0 = (size_t)(b * SEQ + q0 + w * 32 + l15) * 16;
  const size_t mb1 = (size_t)(b * SEQ + q0 + w * 32 + 16 + l15) * 16;

  f16x8 k0r = *(const f16x8*)(kg + (size_t)sr * D3 + sseg * 8);
  f16x8 k1r = *(const f16x8*)(kg + (size_t)(sr + 32) * D3 + sseg * 8);
  f16x8 v0r = *(const f16x8*)(vg + (size_t)vd * SEQ + vs * 8);
  f16x8 v1r = *(const f16x8*)(vg + (size_t)vd * SEQ + 32 + vs * 8);
  unsigned long long mr0 = mb[mb0], mr1 = mb[mb1];

  f32x4 lacc[2];
  f32x4 o_[2][4];
#pragma unroll
  for (int qn = 0; qn < 2; ++qn) {
    lacc[qn] = (f32x4){0.f, 0.f, 0.f, 0.f};
#pragma unroll
    for (int dt = 0; dt < 4; ++dt) o_[qn][dt] = (f32x4){0.f, 0.f, 0.f, 0.f};
  }
  f16x8 ones;
#pragma unroll
  for (int i2 = 0; i2 < 8; ++i2) ones[i2] = (_Float16)1.f;

  for (int kt = 0; kt < 16; ++kt) {
    if (kt) __syncthreads();  // prev iter done reading Ks/Vt
    *(f16x8*)(Ks + sr * 72 + sseg * 8) = k0r;
    *(f16x8*)(Ks + (sr + 32) * 72 + sseg * 8) = k1r;
    *(f16x8*)(Vt + vd * 72 + vs * 8) = v0r;
    *(f16x8*)(Vt + vd * 72 + 32 + vs * 8) = v1r;
    __syncthreads();  // also makes LUT visible before first use
    const unsigned long long mc[2] = {mr0, mr1};
    if (kt < 15) {  // prefetch next tile into regs during compute
      const int kn = (kt + 1) << 6;
      k0r = *(const f16x8*)(kg + (size_t)(kn + sr) * D3 + sseg * 8);
      k1r = *(const f16x8*)(kg + (size_t)(kn + sr + 32) * D3 + sseg * 8);
      v0r = *(const f16x8*)(vg + (size_t)vd * SEQ + kn + vs * 8);
      v1r = *(const f16x8*)(vg + (size_t)vd * SEQ + kn + 32 + vs * 8);
      mr0 = mb[mb0 + kt + 1];
      mr1 = mb[mb1 + kt + 1];
    }
    // S^T = K Q^T (log2-domain scores): col=l15=q, rows mt*16+quad*4+r = k
    f32x4 st[4][2];
#pragma unroll
    for (int mt = 0; mt < 4; ++mt)
#pragma unroll
      for (int qn = 0; qn < 2; ++qn) st[mt][qn] = (f32x4){0.f, 0.f, 0.f, 0.f};
#pragma unroll
    for (int mt = 0; mt < 4; ++mt) {
      f16x8 ka0 = *(const f16x8*)(Ks + (mt * 16 + l15) * 72 + quad * 8);
      f16x8 ka1 = *(const f16x8*)(Ks + (mt * 16 + l15) * 72 + 32 + quad * 8);
#pragma unroll
      for (int qn = 0; qn < 2; ++qn) {
        st[mt][qn] = MFMA16(ka0, qf[qn][0], st[mt][qn]);
        st[mt][qn] = MFMA16(ka1, qf[qn][1], st[mt][qn]);
      }
    }
    // exp2 (no max subtraction) + mask-LUT multiply + store P
#pragma unroll
    for (int qn = 0; qn < 2; ++qn)
#pragma unroll
      for (int mt = 0; mt < 4; ++mt) {
        float e0 = EXP2(fminf(st[mt][qn][0], 15.f));
        float e1 = EXP2(fminf(st[mt][qn][1], 15.f));
        float e2 = EXP2(fminf(st[mt][qn][2], 15.f));
        float e3 = EXP2(fminf(st[mt][qn][3], 15.f));
        h16x2 lo = __builtin_amdgcn_cvt_pkrtz(e0, e1);
        h16x2 hi = __builtin_amdgcn_cvt_pkrtz(e2, e3);
        f16x4 pk;
        pk[0] = (_Float16)lo[0]; pk[1] = (_Float16)lo[1];
        pk[2] = (_Float16)hi[0]; pk[3] = (_Float16)hi[1];
        const unsigned nib = (unsigned)(mc[qn] >> (mt * 16 + quad * 4)) & 15u;
        pk *= *(const f16x4*)LUT[nib];
        *(f16x4*)(&Ps[w][(qn * 16 + l15) * 72 + mt * 16 + quad * 4]) = pk;
      }
    // O += P V ; l += P·1  (wave-private P; V frags shared across q-frags)
    f16x8 pa[2][2];
#pragma unroll
    for (int qn = 0; qn < 2; ++qn) {
      pa[qn][0] = *(const f16x8*)(&Ps[w][(qn * 16 + l15) * 72 + quad * 8]);
      pa[qn][1] = *(const f16x8*)(&Ps[w][(qn * 16 + l15) * 72 + 32 + quad * 8]);
      lacc[qn] = MFMA16(pa[qn][0], ones, lacc[qn]);
      lacc[qn] = MFMA16(pa[qn][1], ones, lacc[qn]);
    }
#pragma unroll
    for (int dt = 0; dt < 4; ++dt) {
      f16x8 vb0 = *(const f16x8*)(Vt + (dt * 16 + l15) * 72 + quad * 8);
      f16x8 vb1 = *(const f16x8*)(Vt + (dt * 16 + l15) * 72 + 32 + quad * 8);
#pragma unroll
      for (int qn = 0; qn < 2; ++qn) {
        o_[qn][dt] = MFMA16(pa[qn][0], vb0, o_[qn][dt]);
        o_[qn][dt] = MFMA16(pa[qn][1], vb1, o_[qn][dt]);
      }
    }
  }
  // normalize + write: lacc rows align with o_ rows -> no shuffles
#pragma unroll
  for (int qn = 0; qn < 2; ++qn) {
    f32x4 inv;
#pragma unroll
    for (int r = 0; r < 4; ++r) inv[r] = 1.f / lacc[qn][r];
#pragma unroll
    for (int dt = 0; dt < 4; ++dt)
#pragma unroll
      for (int r = 0; r < 4; ++r)
        vals[(size_t)(b * SEQ + q0 + w * 32 + qn * 16 + quad * 4 + r) * DM +
             h * HD + dt * 16 + l15] = (_Float16)(o_[qn][dt][r] * inv[r]);
  }
}

extern "C" void kernel_launch(void* const* d_in, const int* in_sizes, int n_in,
                              void* d_out, int out_size, void* d_ws, size_t ws_size,
                              hipStream_t stream) {
  const float* x    = (const float*)d_in[0];
  const int*   mask = (const int*)  d_in[1];
  const float* Wqkv = (const float*)d_in[2];
  const float* bqkv = (const float*)d_in[3];
  const float* Wo   = (const float*)d_in[4];
  const float* bo   = (const float*)d_in[5];
  float* out = (float*)d_out;

  char* ws = (char*)d_ws;
  _Float16* qkv16  = (_Float16*)ws;                    ws += (size_t)BATCH*SEQ*D3*2;   // 24MB (v-cols unused)
  _Float16* vT16   = (_Float16*)ws;                    ws += (size_t)BATCH*DM*SEQ*2;   //  8MB
  _Float16* x16    = (_Float16*)ws;                    ws += (size_t)BATCH*SEQ*DM*2;   //  8MB
  _Float16* WqkvT  = (_Float16*)ws;                    ws += (size_t)DM*D3*2;          //  6MB
  _Float16* WoT    = (_Float16*)ws;                    ws += (size_t)DM*DM*2;          //  2MB
  _Float16* vals16 = (_Float16*)ws;                    ws += (size_t)BATCH*SEQ*DM*2;   //  8MB
  unsigned long long* mbits = (unsigned long long*)ws;                                 // 0.5MB

  // transpose blocks first (they feed the GEMM B operand), then cast, then mask
  prep_all<<<3072 + (BATCH*SEQ*SEQ)/256, 256, 0, stream>>>(
      x, x16, mask, mbits, Wqkv, WqkvT, Wo, WoT);

  gemm_bt<_Float16, true, 128><<<dim3(D3/128, BATCH*SEQ/128), 256, 0, stream>>>(
      x16, WqkvT, bqkv, qkv16, vT16, BATCH*SEQ, D3, DM);
  attn<<<512, 256, 0, stream>>>(qkv16, vT16, mbits, vals16);
  gemm_bt<float, false, 64><<<dim3(DM/64, (BATCH*SEQ)/128), 256, 0, stream>>>(
      vals16, WoT, bo, out, nullptr, BATCH*SEQ, DM, DM);
}

// Round 4
// 186.094 us; speedup vs baseline: 1.0474x; 1.0217x over previous
//
#include <hip/hip_runtime.h>
#include <cstddef>
#include <cstdint>

#define BATCH 4
#define SEQ   1024
#define DM    1024
#define NH    16
#define HD    64
#define D3    3072
#define LOG2E 1.44269504088896340736f
#define QSCALE (0.125f * LOG2E)

typedef _Float16 f16x8 __attribute__((ext_vector_type(8)));
typedef _Float16 f16x4 __attribute__((ext_vector_type(4)));
typedef __fp16   h16x2 __attribute__((ext_vector_type(2)));
typedef float    f32x4 __attribute__((ext_vector_type(4)));

#define MFMA16(a, b, c) __builtin_amdgcn_mfma_f32_16x16x32_f16((a), (b), (c), 0, 0, 0)
#define GLD_LDS16(gp, lp) \
  __builtin_amdgcn_global_load_lds((const __attribute__((address_space(1))) unsigned int*)(gp), \
                                   (__attribute__((address_space(3))) unsigned int*)(lp), 16, 0, 0)
#if __has_builtin(__builtin_amdgcn_exp2f)
#define EXP2(x) __builtin_amdgcn_exp2f(x)
#else
#define EXP2(x) exp2f(x)
#endif

// ---------- fused prologue: weight transpose (blocks 0..1023) + x cast
// (1024..3071) + mask pack (3072..). All memory-bound & independent ->
// one launch lets them share the BW shadow instead of running serially.
// ~80MB total traffic ~= 13us: already at the BW roofline.
__global__ __launch_bounds__(256) void prep_all(const float* __restrict__ x,
                                                _Float16* __restrict__ x16,
                                                const int* __restrict__ mask,
                                                unsigned long long* __restrict__ mb,
                                                const float* __restrict__ W1,
                                                _Float16* __restrict__ WT1,
                                                const float* __restrict__ W2,
                                                _Float16* __restrict__ WT2) {
  __shared__ _Float16 T[64 * 72];
  const int tid = threadIdx.x;
  const int bx = blockIdx.x;
  if (bx < 1024) {  // transpose W[K][N] -> WT[N][K], 64x64 tiles
    const int tx = bx & 63, ty = bx >> 6;
    const bool first = tx < 48;
    const float* W = first ? W1 : W2;
    _Float16* WT = first ? WT1 : WT2;
    const int N = first ? D3 : DM;
    const int K = DM;
    const int c0 = (first ? tx : (tx - 48)) * 64;
    const int r0 = ty * 64;
#pragma unroll
    for (int it = 0; it < 4; ++it) {
      const int row = it * 16 + (tid >> 4);
      const int col4 = (tid & 15) * 4;
      float4 wv = *(const float4*)(W + (size_t)(r0 + row) * N + c0 + col4);
      T[(col4 + 0) * 72 + row] = (_Float16)wv.x;
      T[(col4 + 1) * 72 + row] = (_Float16)wv.y;
      T[(col4 + 2) * 72 + row] = (_Float16)wv.z;
      T[(col4 + 3) * 72 + row] = (_Float16)wv.w;
    }
    __syncthreads();
#pragma unroll
    for (int it = 0; it < 2; ++it) {
      const int g = it * 256 + tid;
      const int col = g >> 3, seg = g & 7;
      *(f16x8*)(WT + (size_t)(c0 + col) * K + r0 + seg * 8) =
          *(const f16x8*)(T + col * 72 + seg * 8);
    }
  } else if (bx < 3072) {  // fp32 -> fp16 cast of x
    const int i = (bx - 1024) * 256 + tid;
    float4 a = ((const float4*)x)[i * 2];
    float4 b = ((const float4*)x)[i * 2 + 1];
    f16x8 o;
    o[0] = (_Float16)a.x; o[1] = (_Float16)a.y; o[2] = (_Float16)a.z; o[3] = (_Float16)a.w;
    o[4] = (_Float16)b.x; o[5] = (_Float16)b.y; o[6] = (_Float16)b.z; o[7] = (_Float16)b.w;
    ((f16x8*)x16)[i] = o;
  } else {  // mask -> bitmask
    const size_t i = (size_t)(bx - 3072) * 256 + tid;
    const int m = mask[i];
    unsigned long long bits = __ballot(m != 0);
    if ((tid & 63) == 0) mb[i >> 6] = bits;
  }
}

// ---------- GEMM: C[M][N] = A * BT^T + bias. XOR-swizzled LDS ----------
// 2-barrier m97 structure; relies on >=2 blocks/CU for cross-block overlap of
// the vmcnt(0)+barrier drain (m114).
//  QKV:    TN=128, BK=64  -> 768 blocks (~3/CU), 32 MFMA per drain.
//  O-proj: TN=64,  BK=128 -> 512 blocks (2/CU; LDS 48KB still fits 2),
//          8 K-steps instead of 16 -> half the drains, 32 MFMA per drain.
//          (m132's BK=128 regression was an occupancy cliff 3->2 at 64KB LDS;
//           here occupancy is grid-limited at 2 either way.)
template <typename OutT, bool QKV, int TN, int BK>
__global__ __launch_bounds__(256) void gemm_bt(const _Float16* __restrict__ A,
                                               const _Float16* __restrict__ BT,
                                               const float* __restrict__ bias,
                                               OutT* __restrict__ C,
                                               _Float16* __restrict__ vTp,
                                               int M, int N, int K) {
  constexpr int NT = TN / 32;   // n-frags per wave
  constexpr int CH = BK / 8;    // 16B chunks per LDS row
  __shared__ _Float16 As[128 * BK];
  __shared__ _Float16 Bs[TN * BK];
  const int tid = threadIdx.x;
  const int l15 = tid & 15;
  const int quad = (tid & 63) >> 4;
  const int w = tid >> 6;
  const int wm = w >> 1, wn = w & 1;
  const int rowbase = blockIdx.y * 128;
  const int colbase = blockIdx.x * TN;

  f32x4 acc[4][NT];
#pragma unroll
  for (int mt = 0; mt < 4; ++mt)
#pragma unroll
    for (int nt = 0; nt < NT; ++nt) acc[mt][nt] = (f32x4){0.f, 0.f, 0.f, 0.f};

  for (int k0 = 0; k0 < K; k0 += BK) {
    __syncthreads();  // readers of prev tile done
    // stage A/B: chunk-slot g -> row r = g/CH, slot s = g%CH; the LDS dest is
    // linear (gload_lds constraint); source chunk = s ^ (r & (CH-1)) so that a
    // swizzled READ is conflict-free (16 rows hit distinct chunk slots).
#pragma unroll
    for (int it = 0; it < 128 * CH / 256; ++it) {
      const int g = it * 256 + tid;
      const int r = g / CH, cs = (g & (CH - 1)) ^ (r & (CH - 1));
      GLD_LDS16(A + (size_t)(rowbase + r) * K + k0 + cs * 8, As + g * 8);
    }
#pragma unroll
    for (int it = 0; it < TN * CH / 256; ++it) {
      const int g = it * 256 + tid;
      const int r = g / CH, cs = (g & (CH - 1)) ^ (r & (CH - 1));
      GLD_LDS16(BT + (size_t)(colbase + r) * K + k0 + cs * 8, Bs + g * 8);
    }
    __syncthreads();  // DMA writes visible (compiler drains vmcnt)
#pragma unroll
    for (int kh = 0; kh < BK / 32; ++kh) {
      f16x8 a[4], b[NT];
#pragma unroll
      for (int mt = 0; mt < 4; ++mt) {
        const int row = wm * 64 + mt * 16 + l15;
        a[mt] = *(const f16x8*)(As + row * BK +
                                (((kh * 4 + quad) ^ (row & (CH - 1))) << 3));
      }
#pragma unroll
      for (int nt = 0; nt < NT; ++nt) {
        const int row = wn * (TN / 2) + nt * 16 + l15;
        b[nt] = *(const f16x8*)(Bs + row * BK +
                                (((kh * 4 + quad) ^ (row & (CH - 1))) << 3));
      }
#pragma unroll
      for (int mt = 0; mt < 4; ++mt)
#pragma unroll
        for (int nt = 0; nt < NT; ++nt)
          acc[mt][nt] = MFMA16(a[mt], b[nt], acc[mt][nt]);
    }
  }

  float bv[NT];
#pragma unroll
  for (int nt = 0; nt < NT; ++nt) bv[nt] = bias[colbase + wn * (TN / 2) + nt * 16 + l15];
#pragma unroll
  for (int mt = 0; mt < 4; ++mt)
#pragma unroll
    for (int nt = 0; nt < NT; ++nt) {
      const int col = colbase + wn * (TN / 2) + nt * 16 + l15;
      if (QKV) {
        const int reg3 = (col >> 6) % 3;  // wave-uniform
        if (reg3 == 2) {
          const int hh = col / 192;
          const int d = col - hh * 192 - 128;
          const int row0 = rowbase + wm * 64 + mt * 16 + quad * 4;
          const int bb = row0 >> 10, s0 = row0 & 1023;
          f16x4 pk;
#pragma unroll
          for (int r = 0; r < 4; ++r) pk[r] = (_Float16)(acc[mt][nt][r] + bv[nt]);
          *(f16x4*)(vTp + ((size_t)((bb * NH + hh) * HD + d)) * SEQ + s0) = pk;
        } else {
          const float sc = (reg3 == 0) ? QSCALE : 1.f;  // q: fold 1/8 * log2(e)
#pragma unroll
          for (int r = 0; r < 4; ++r) {
            const int row = rowbase + wm * 64 + mt * 16 + quad * 4 + r;
            C[(size_t)row * N + col] = (OutT)((acc[mt][nt][r] + bv[nt]) * sc);
          }
        }
      } else {
#pragma unroll
        for (int r = 0; r < 4; ++r) {
          const int row = rowbase + wm * 64 + mt * 16 + quad * 4 + r;
          C[(size_t)row * N + col] = (OutT)(acc[mt][nt][r] + bv[nt]);
        }
      }
    }
}

// ---------- MFMA flash attention v3 + XCD swizzle ----------
// 1D grid 512: i = outer*64 + qtile*8 + xcd; blocks sharing (b,h) keep i%8
// constant -> same XCD -> K/V L2 reuse (2MB/XCD < 4MB L2).
__global__ __launch_bounds__(256) void attn(const _Float16* __restrict__ qkv,
                                            const _Float16* __restrict__ vT,
                                            const unsigned long long* __restrict__ mb,
                                            _Float16* __restrict__ vals) {
  __shared__ _Float16 Ks[64 * 72];
  __shared__ _Float16 Vt[64 * 72];       // Vt[d][sk]
  __shared__ _Float16 Ps[4][32 * 72];    // per-wave P [32 q][64 k]
  __shared__ __align__(8) _Float16 LUT[16][4];
  const int tid = threadIdx.x;
  const int l15 = tid & 15, quad = (tid & 63) >> 4, w = tid >> 6;
  const int i = blockIdx.x;
  const int bh = (i >> 6) * 8 + (i & 7);
  const int b = bh >> 4, h = bh & 15;
  const int q0 = ((i >> 3) & 7) << 7;    // 128-row q tile

  if (tid < 16) {
    LUT[tid][0] = (tid & 1) ? (_Float16)1.f : (_Float16)0.f;
    LUT[tid][1] = (tid & 2) ? (_Float16)1.f : (_Float16)0.f;
    LUT[tid][2] = (tid & 4) ? (_Float16)1.f : (_Float16)0.f;
    LUT[tid][3] = (tid & 8) ? (_Float16)1.f : (_Float16)0.f;
  }

  const _Float16* qb = qkv + (size_t)b * SEQ * D3 + h * 192;
  f16x8 qf[2][2];
#pragma unroll
  for (int qn = 0; qn < 2; ++qn)
#pragma unroll
    for (int hf = 0; hf < 2; ++hf)
      qf[qn][hf] = *(const f16x8*)(qb + (size_t)(q0 + w * 32 + qn * 16 + l15) * D3 +
                                   hf * 32 + quad * 8);

  const _Float16* kg = qb + 64;
  const _Float16* vg = vT + (size_t)((b * NH + h) * HD) * SEQ;
  const int sr = tid >> 3, sseg = tid & 7;  // K staging: rows sr, sr+32
  const int vd = tid >> 2, vs = tid & 3;    // V staging: row vd, segs vs, vs+4
  const size_t mb0 = (size_t)(b * SEQ + q0 + w * 32 + l15) * 16;
  const size_t mb1 = (size_t)(b * SEQ + q0 + w * 32 + 16 + l15) * 16;

  f16x8 k0r = *(const f16x8*)(kg + (size_t)sr * D3 + sseg * 8);
  f16x8 k1r = *(const f16x8*)(kg + (size_t)(sr + 32) * D3 + sseg * 8);
  f16x8 v0r = *(const f16x8*)(vg + (size_t)vd * SEQ + vs * 8);
  f16x8 v1r = *(const f16x8*)(vg + (size_t)vd * SEQ + 32 + vs * 8);
  unsigned long long mr0 = mb[mb0], mr1 = mb[mb1];

  f32x4 lacc[2];
  f32x4 o_[2][4];
#pragma unroll
  for (int qn = 0; qn < 2; ++qn) {
    lacc[qn] = (f32x4){0.f, 0.f, 0.f, 0.f};
#pragma unroll
    for (int dt = 0; dt < 4; ++dt) o_[qn][dt] = (f32x4){0.f, 0.f, 0.f, 0.f};
  }
  f16x8 ones;
#pragma unroll
  for (int i2 = 0; i2 < 8; ++i2) ones[i2] = (_Float16)1.f;

  for (int kt = 0; kt < 16; ++kt) {
    if (kt) __syncthreads();  // prev iter done reading Ks/Vt
    *(f16x8*)(Ks + sr * 72 + sseg * 8) = k0r;
    *(f16x8*)(Ks + (sr + 32) * 72 + sseg * 8) = k1r;
    *(f16x8*)(Vt + vd * 72 + vs * 8) = v0r;
    *(f16x8*)(Vt + vd * 72 + 32 + vs * 8) = v1r;
    __syncthreads();  // also makes LUT visible before first use
    const unsigned long long mc[2] = {mr0, mr1};
    if (kt < 15) {  // prefetch next tile into regs during compute
      const int kn = (kt + 1) << 6;
      k0r = *(const f16x8*)(kg + (size_t)(kn + sr) * D3 + sseg * 8);
      k1r = *(const f16x8*)(kg + (size_t)(kn + sr + 32) * D3 + sseg * 8);
      v0r = *(const f16x8*)(vg + (size_t)vd * SEQ + kn + vs * 8);
      v1r = *(const f16x8*)(vg + (size_t)vd * SEQ + kn + 32 + vs * 8);
      mr0 = mb[mb0 + kt + 1];
      mr1 = mb[mb1 + kt + 1];
    }
    // S^T = K Q^T (log2-domain scores): col=l15=q, rows mt*16+quad*4+r = k
    f32x4 st[4][2];
#pragma unroll
    for (int mt = 0; mt < 4; ++mt)
#pragma unroll
      for (int qn = 0; qn < 2; ++qn) st[mt][qn] = (f32x4){0.f, 0.f, 0.f, 0.f};
#pragma unroll
    for (int mt = 0; mt < 4; ++mt) {
      f16x8 ka0 = *(const f16x8*)(Ks + (mt * 16 + l15) * 72 + quad * 8);
      f16x8 ka1 = *(const f16x8*)(Ks + (mt * 16 + l15) * 72 + 32 + quad * 8);
#pragma unroll
      for (int qn = 0; qn < 2; ++qn) {
        st[mt][qn] = MFMA16(ka0, qf[qn][0], st[mt][qn]);
        st[mt][qn] = MFMA16(ka1, qf[qn][1], st[mt][qn]);
      }
    }
    // exp2 (no max subtraction) + mask-LUT multiply + store P
#pragma unroll
    for (int qn = 0; qn < 2; ++qn)
#pragma unroll
      for (int mt = 0; mt < 4; ++mt) {
        float e0 = EXP2(fminf(st[mt][qn][0], 15.f));
        float e1 = EXP2(fminf(st[mt][qn][1], 15.f));
        float e2 = EXP2(fminf(st[mt][qn][2], 15.f));
        float e3 = EXP2(fminf(st[mt][qn][3], 15.f));
        h16x2 lo = __builtin_amdgcn_cvt_pkrtz(e0, e1);
        h16x2 hi = __builtin_amdgcn_cvt_pkrtz(e2, e3);
        f16x4 pk;
        pk[0] = (_Float16)lo[0]; pk[1] = (_Float16)lo[1];
        pk[2] = (_Float16)hi[0]; pk[3] = (_Float16)hi[1];
        const unsigned nib = (unsigned)(mc[qn] >> (mt * 16 + quad * 4)) & 15u;
        pk *= *(const f16x4*)LUT[nib];
        *(f16x4*)(&Ps[w][(qn * 16 + l15) * 72 + mt * 16 + quad * 4]) = pk;
      }
    // O += P V ; l += P·1  (wave-private P; V frags shared across q-frags)
    f16x8 pa[2][2];
#pragma unroll
    for (int qn = 0; qn < 2; ++qn) {
      pa[qn][0] = *(const f16x8*)(&Ps[w][(qn * 16 + l15) * 72 + quad * 8]);
      pa[qn][1] = *(const f16x8*)(&Ps[w][(qn * 16 + l15) * 72 + 32 + quad * 8]);
      lacc[qn] = MFMA16(pa[qn][0], ones, lacc[qn]);
      lacc[qn] = MFMA16(pa[qn][1], ones, lacc[qn]);
    }
#pragma unroll
    for (int dt = 0; dt < 4; ++dt) {
      f16x8 vb0 = *(const f16x8*)(Vt + (dt * 16 + l15) * 72 + quad * 8);
      f16x8 vb1 = *(const f16x8*)(Vt + (dt * 16 + l15) * 72 + 32 + quad * 8);
#pragma unroll
      for (int qn = 0; qn < 2; ++qn) {
        o_[qn][dt] = MFMA16(pa[qn][0], vb0, o_[qn][dt]);
        o_[qn][dt] = MFMA16(pa[qn][1], vb1, o_[qn][dt]);
      }
    }
  }
  // normalize + write: lacc rows align with o_ rows -> no shuffles
#pragma unroll
  for (int qn = 0; qn < 2; ++qn) {
    f32x4 inv;
#pragma unroll
    for (int r = 0; r < 4; ++r) inv[r] = 1.f / lacc[qn][r];
#pragma unroll
    for (int dt = 0; dt < 4; ++dt)
#pragma unroll
      for (int r = 0; r < 4; ++r)
        vals[(size_t)(b * SEQ + q0 + w * 32 + qn * 16 + quad * 4 + r) * DM +
             h * HD + dt * 16 + l15] = (_Float16)(o_[qn][dt][r] * inv[r]);
  }
}

extern "C" void kernel_launch(void* const* d_in, const int* in_sizes, int n_in,
                              void* d_out, int out_size, void* d_ws, size_t ws_size,
                              hipStream_t stream) {
  const float* x    = (const float*)d_in[0];
  const int*   mask = (const int*)  d_in[1];
  const float* Wqkv = (const float*)d_in[2];
  const float* bqkv = (const float*)d_in[3];
  const float* Wo   = (const float*)d_in[4];
  const float* bo   = (const float*)d_in[5];
  float* out = (float*)d_out;

  char* ws = (char*)d_ws;
  _Float16* qkv16  = (_Float16*)ws;                    ws += (size_t)BATCH*SEQ*D3*2;   // 24MB (v-cols unused)
  _Float16* vT16   = (_Float16*)ws;                    ws += (size_t)BATCH*DM*SEQ*2;   //  8MB
  _Float16* x16    = (_Float16*)ws;                    ws += (size_t)BATCH*SEQ*DM*2;   //  8MB
  _Float16* WqkvT  = (_Float16*)ws;                    ws += (size_t)DM*D3*2;          //  6MB
  _Float16* WoT    = (_Float16*)ws;                    ws += (size_t)DM*DM*2;          //  2MB
  _Float16* vals16 = (_Float16*)ws;                    ws += (size_t)BATCH*SEQ*DM*2;   //  8MB
  unsigned long long* mbits = (unsigned long long*)ws;                                 // 0.5MB

  // transpose blocks first (they feed the GEMM B operand), then cast, then mask
  prep_all<<<3072 + (BATCH*SEQ*SEQ)/256, 256, 0, stream>>>(
      x, x16, mask, mbits, Wqkv, WqkvT, Wo, WoT);

  gemm_bt<_Float16, true, 128, 64><<<dim3(D3/128, BATCH*SEQ/128), 256, 0, stream>>>(
      x16, WqkvT, bqkv, qkv16, vT16, BATCH*SEQ, D3, DM);
  attn<<<512, 256, 0, stream>>>(qkv16, vT16, mbits, vals16);
  gemm_bt<float, false, 64, 128><<<dim3(DM/64, (BATCH*SEQ)/128), 256, 0, stream>>>(
      vals16, WoT, bo, out, nullptr, BATCH*SEQ, DM, DM);
}

// Round 5
// 179.158 us; speedup vs baseline: 1.0879x; 1.0387x over previous
//
#include <hip/hip_runtime.h>
#include <cstddef>
#include <cstdint>

#define BATCH 4
#define SEQ   1024
#define DM    1024
#define NH    16
#define HD    64
#define D3    3072
#define LOG2E 1.44269504088896340736f
#define QSCALE (0.125f * LOG2E)

typedef _Float16 f16x8 __attribute__((ext_vector_type(8)));
typedef _Float16 f16x4 __attribute__((ext_vector_type(4)));
typedef __fp16   h16x2 __attribute__((ext_vector_type(2)));
typedef float    f32x4 __attribute__((ext_vector_type(4)));

#define MFMA16(a, b, c) __builtin_amdgcn_mfma_f32_16x16x32_f16((a), (b), (c), 0, 0, 0)
#define GLD_LDS16(gp, lp) \
  __builtin_amdgcn_global_load_lds((const __attribute__((address_space(1))) unsigned int*)(gp), \
                                   (__attribute__((address_space(3))) unsigned int*)(lp), 16, 0, 0)
#if __has_builtin(__builtin_amdgcn_exp2f)
#define EXP2(x) __builtin_amdgcn_exp2f(x)
#else
#define EXP2(x) exp2f(x)
#endif

// ---------- fused prologue: weight transpose (blocks 0..1023) + x cast
// (1024..3071) + mask pack (3072..). All memory-bound & independent ->
// one launch lets them share the BW shadow instead of running serially.
// ~66MB total traffic ~= 11-13us: at the BW roofline.
__global__ __launch_bounds__(256) void prep_all(const float* __restrict__ x,
                                                _Float16* __restrict__ x16,
                                                const int* __restrict__ mask,
                                                unsigned long long* __restrict__ mb,
                                                const float* __restrict__ W1,
                                                _Float16* __restrict__ WT1,
                                                const float* __restrict__ W2,
                                                _Float16* __restrict__ WT2) {
  __shared__ _Float16 T[64 * 72];
  const int tid = threadIdx.x;
  const int bx = blockIdx.x;
  if (bx < 1024) {  // transpose W[K][N] -> WT[N][K], 64x64 tiles
    const int tx = bx & 63, ty = bx >> 6;
    const bool first = tx < 48;
    const float* W = first ? W1 : W2;
    _Float16* WT = first ? WT1 : WT2;
    const int N = first ? D3 : DM;
    const int K = DM;
    const int c0 = (first ? tx : (tx - 48)) * 64;
    const int r0 = ty * 64;
#pragma unroll
    for (int it = 0; it < 4; ++it) {
      const int row = it * 16 + (tid >> 4);
      const int col4 = (tid & 15) * 4;
      float4 wv = *(const float4*)(W + (size_t)(r0 + row) * N + c0 + col4);
      T[(col4 + 0) * 72 + row] = (_Float16)wv.x;
      T[(col4 + 1) * 72 + row] = (_Float16)wv.y;
      T[(col4 + 2) * 72 + row] = (_Float16)wv.z;
      T[(col4 + 3) * 72 + row] = (_Float16)wv.w;
    }
    __syncthreads();
#pragma unroll
    for (int it = 0; it < 2; ++it) {
      const int g = it * 256 + tid;
      const int col = g >> 3, seg = g & 7;
      *(f16x8*)(WT + (size_t)(c0 + col) * K + r0 + seg * 8) =
          *(const f16x8*)(T + col * 72 + seg * 8);
    }
  } else if (bx < 3072) {  // fp32 -> fp16 cast of x
    const int i = (bx - 1024) * 256 + tid;
    float4 a = ((const float4*)x)[i * 2];
    float4 b = ((const float4*)x)[i * 2 + 1];
    f16x8 o;
    o[0] = (_Float16)a.x; o[1] = (_Float16)a.y; o[2] = (_Float16)a.z; o[3] = (_Float16)a.w;
    o[4] = (_Float16)b.x; o[5] = (_Float16)b.y; o[6] = (_Float16)b.z; o[7] = (_Float16)b.w;
    ((f16x8*)x16)[i] = o;
  } else {  // mask -> bitmask
    const size_t i = (size_t)(bx - 3072) * 256 + tid;
    const int m = mask[i];
    unsigned long long bits = __ballot(m != 0);
    if ((tid & 63) == 0) mb[i >> 6] = bits;
  }
}

// ---------- GEMM: C[M][N] = A * BT^T + bias. XOR-swizzled LDS ----------
// 2-barrier m97 structure; relies on >=2 blocks/CU for cross-block overlap of
// the vmcnt(0)+barrier drain (m114).
//  QKV:    TN=128, BK=64  -> 768 blocks (~3/CU), 32 MFMA per drain.
//  O-proj: TN=64,  BK=128 -> 512 blocks (2/CU; LDS 48KB still fits 2),
//          8 K-steps instead of 16 -> half the drains, 32 MFMA per drain.
template <typename OutT, bool QKV, int TN, int BK>
__global__ __launch_bounds__(256) void gemm_bt(const _Float16* __restrict__ A,
                                               const _Float16* __restrict__ BT,
                                               const float* __restrict__ bias,
                                               OutT* __restrict__ C,
                                               _Float16* __restrict__ vTp,
                                               int M, int N, int K) {
  constexpr int NT = TN / 32;   // n-frags per wave
  constexpr int CH = BK / 8;    // 16B chunks per LDS row
  __shared__ _Float16 As[128 * BK];
  __shared__ _Float16 Bs[TN * BK];
  const int tid = threadIdx.x;
  const int l15 = tid & 15;
  const int quad = (tid & 63) >> 4;
  const int w = tid >> 6;
  const int wm = w >> 1, wn = w & 1;
  const int rowbase = blockIdx.y * 128;
  const int colbase = blockIdx.x * TN;

  f32x4 acc[4][NT];
#pragma unroll
  for (int mt = 0; mt < 4; ++mt)
#pragma unroll
    for (int nt = 0; nt < NT; ++nt) acc[mt][nt] = (f32x4){0.f, 0.f, 0.f, 0.f};

  for (int k0 = 0; k0 < K; k0 += BK) {
    __syncthreads();  // readers of prev tile done
#pragma unroll
    for (int it = 0; it < 128 * CH / 256; ++it) {
      const int g = it * 256 + tid;
      const int r = g / CH, cs = (g & (CH - 1)) ^ (r & (CH - 1));
      GLD_LDS16(A + (size_t)(rowbase + r) * K + k0 + cs * 8, As + g * 8);
    }
#pragma unroll
    for (int it = 0; it < TN * CH / 256; ++it) {
      const int g = it * 256 + tid;
      const int r = g / CH, cs = (g & (CH - 1)) ^ (r & (CH - 1));
      GLD_LDS16(BT + (size_t)(colbase + r) * K + k0 + cs * 8, Bs + g * 8);
    }
    __syncthreads();  // DMA writes visible (compiler drains vmcnt)
#pragma unroll
    for (int kh = 0; kh < BK / 32; ++kh) {
      f16x8 a[4], b[NT];
#pragma unroll
      for (int mt = 0; mt < 4; ++mt) {
        const int row = wm * 64 + mt * 16 + l15;
        a[mt] = *(const f16x8*)(As + row * BK +
                                (((kh * 4 + quad) ^ (row & (CH - 1))) << 3));
      }
#pragma unroll
      for (int nt = 0; nt < NT; ++nt) {
        const int row = wn * (TN / 2) + nt * 16 + l15;
        b[nt] = *(const f16x8*)(Bs + row * BK +
                                (((kh * 4 + quad) ^ (row & (CH - 1))) << 3));
      }
#pragma unroll
      for (int mt = 0; mt < 4; ++mt)
#pragma unroll
        for (int nt = 0; nt < NT; ++nt)
          acc[mt][nt] = MFMA16(a[mt], b[nt], acc[mt][nt]);
    }
  }

  float bv[NT];
#pragma unroll
  for (int nt = 0; nt < NT; ++nt) bv[nt] = bias[colbase + wn * (TN / 2) + nt * 16 + l15];
#pragma unroll
  for (int mt = 0; mt < 4; ++mt)
#pragma unroll
    for (int nt = 0; nt < NT; ++nt) {
      const int col = colbase + wn * (TN / 2) + nt * 16 + l15;
      if (QKV) {
        const int reg3 = (col >> 6) % 3;  // wave-uniform
        if (reg3 == 2) {
          const int hh = col / 192;
          const int d = col - hh * 192 - 128;
          const int row0 = rowbase + wm * 64 + mt * 16 + quad * 4;
          const int bb = row0 >> 10, s0 = row0 & 1023;
          f16x4 pk;
#pragma unroll
          for (int r = 0; r < 4; ++r) pk[r] = (_Float16)(acc[mt][nt][r] + bv[nt]);
          *(f16x4*)(vTp + ((size_t)((bb * NH + hh) * HD + d)) * SEQ + s0) = pk;
        } else {
          const float sc = (reg3 == 0) ? QSCALE : 1.f;  // q: fold 1/8 * log2(e)
#pragma unroll
          for (int r = 0; r < 4; ++r) {
            const int row = rowbase + wm * 64 + mt * 16 + quad * 4 + r;
            C[(size_t)row * N + col] = (OutT)((acc[mt][nt][r] + bv[nt]) * sc);
          }
        }
      } else {
#pragma unroll
        for (int r = 0; r < 4; ++r) {
          const int row = rowbase + wm * 64 + mt * 16 + quad * 4 + r;
          C[(size_t)row * N + col] = (OutT)(acc[mt][nt][r] + bv[nt]);
        }
      }
    }
}

// ---------- MFMA flash attention v4: double-buffered K/V, 1 barrier/tile ----
// XCD swizzle: 1D grid 512: i = outer*64 + qtile*8 + xcd; blocks sharing (b,h)
// keep i%8 constant -> same XCD -> K/V L2 reuse.
// Pipe model: LDS-bound (ka/vb re-read by all 4 waves). v4 removes one of the
// two per-tile barriers by writing tile t+1 into the idle buffer DURING tile-t
// compute (hazard: buf was last read at t-1, barrier-separated; writes become
// visible via the single end-of-iter barrier). setprio(1) wraps MFMA clusters
// (T5, +4-7% attn, m191).
__global__ __launch_bounds__(256) void attn(const _Float16* __restrict__ qkv,
                                            const _Float16* __restrict__ vT,
                                            const unsigned long long* __restrict__ mb,
                                            _Float16* __restrict__ vals) {
  __shared__ _Float16 Ks[2][64 * 72];
  __shared__ _Float16 Vt[2][64 * 72];    // Vt[d][sk]
  __shared__ _Float16 Ps[4][32 * 72];    // per-wave P [32 q][64 k]
  __shared__ __align__(8) _Float16 LUT[16][4];
  const int tid = threadIdx.x;
  const int l15 = tid & 15, quad = (tid & 63) >> 4, w = tid >> 6;
  const int i = blockIdx.x;
  const int bh = (i >> 6) * 8 + (i & 7);
  const int b = bh >> 4, h = bh & 15;
  const int q0 = ((i >> 3) & 7) << 7;    // 128-row q tile

  if (tid < 16) {
    LUT[tid][0] = (tid & 1) ? (_Float16)1.f : (_Float16)0.f;
    LUT[tid][1] = (tid & 2) ? (_Float16)1.f : (_Float16)0.f;
    LUT[tid][2] = (tid & 4) ? (_Float16)1.f : (_Float16)0.f;
    LUT[tid][3] = (tid & 8) ? (_Float16)1.f : (_Float16)0.f;
  }

  const _Float16* qb = qkv + (size_t)b * SEQ * D3 + h * 192;
  f16x8 qf[2][2];
#pragma unroll
  for (int qn = 0; qn < 2; ++qn)
#pragma unroll
    for (int hf = 0; hf < 2; ++hf)
      qf[qn][hf] = *(const f16x8*)(qb + (size_t)(q0 + w * 32 + qn * 16 + l15) * D3 +
                                   hf * 32 + quad * 8);

  const _Float16* kg = qb + 64;
  const _Float16* vg = vT + (size_t)((b * NH + h) * HD) * SEQ;
  const int sr = tid >> 3, sseg = tid & 7;  // K staging: rows sr, sr+32
  const int vd = tid >> 2, vs = tid & 3;    // V staging: row vd, segs vs, vs+4
  const size_t mb0 = (size_t)(b * SEQ + q0 + w * 32 + l15) * 16;
  const size_t mb1 = (size_t)(b * SEQ + q0 + w * 32 + 16 + l15) * 16;

  // tile 0: load -> write buf0
  f16x8 k0r = *(const f16x8*)(kg + (size_t)sr * D3 + sseg * 8);
  f16x8 k1r = *(const f16x8*)(kg + (size_t)(sr + 32) * D3 + sseg * 8);
  f16x8 v0r = *(const f16x8*)(vg + (size_t)vd * SEQ + vs * 8);
  f16x8 v1r = *(const f16x8*)(vg + (size_t)vd * SEQ + 32 + vs * 8);
  unsigned long long mcur0 = mb[mb0], mcur1 = mb[mb1];
  *(f16x8*)(Ks[0] + sr * 72 + sseg * 8) = k0r;
  *(f16x8*)(Ks[0] + (sr + 32) * 72 + sseg * 8) = k1r;
  *(f16x8*)(Vt[0] + vd * 72 + vs * 8) = v0r;
  *(f16x8*)(Vt[0] + vd * 72 + 32 + vs * 8) = v1r;
  // prefetch tile 1 into regs
  k0r = *(const f16x8*)(kg + (size_t)(64 + sr) * D3 + sseg * 8);
  k1r = *(const f16x8*)(kg + (size_t)(64 + sr + 32) * D3 + sseg * 8);
  v0r = *(const f16x8*)(vg + (size_t)vd * SEQ + 64 + vs * 8);
  v1r = *(const f16x8*)(vg + (size_t)vd * SEQ + 96 + vs * 8);
  unsigned long long mnxt0 = mb[mb0 + 1], mnxt1 = mb[mb1 + 1];

  f32x4 lacc[2];
  f32x4 o_[2][4];
#pragma unroll
  for (int qn = 0; qn < 2; ++qn) {
    lacc[qn] = (f32x4){0.f, 0.f, 0.f, 0.f};
#pragma unroll
    for (int dt = 0; dt < 4; ++dt) o_[qn][dt] = (f32x4){0.f, 0.f, 0.f, 0.f};
  }
  f16x8 ones;
#pragma unroll
  for (int i2 = 0; i2 < 8; ++i2) ones[i2] = (_Float16)1.f;

  __syncthreads();  // tile0 + LUT visible

  for (int kt = 0; kt < 16; ++kt) {
    const int cur = kt & 1;
    const _Float16* Kc = Ks[cur];
    const _Float16* Vc = Vt[cur];
    // write tile kt+1 (in regs) into the idle buffer; overlaps compute below
    if (kt < 15) {
      _Float16* Kn = Ks[cur ^ 1];
      _Float16* Vn = Vt[cur ^ 1];
      *(f16x8*)(Kn + sr * 72 + sseg * 8) = k0r;
      *(f16x8*)(Kn + (sr + 32) * 72 + sseg * 8) = k1r;
      *(f16x8*)(Vn + vd * 72 + vs * 8) = v0r;
      *(f16x8*)(Vn + vd * 72 + 32 + vs * 8) = v1r;
    }
    const unsigned long long mc[2] = {mcur0, mcur1};
    mcur0 = mnxt0; mcur1 = mnxt1;
    if (kt < 14) {  // issue loads for tile kt+2; land during next iteration
      const int kn = (kt + 2) << 6;
      k0r = *(const f16x8*)(kg + (size_t)(kn + sr) * D3 + sseg * 8);
      k1r = *(const f16x8*)(kg + (size_t)(kn + sr + 32) * D3 + sseg * 8);
      v0r = *(const f16x8*)(vg + (size_t)vd * SEQ + kn + vs * 8);
      v1r = *(const f16x8*)(vg + (size_t)vd * SEQ + kn + 32 + vs * 8);
      mnxt0 = mb[mb0 + kt + 2];
      mnxt1 = mb[mb1 + kt + 2];
    }
    // S^T = K Q^T (log2-domain scores): col=l15=q, rows mt*16+quad*4+r = k
    f32x4 st[4][2];
#pragma unroll
    for (int mt = 0; mt < 4; ++mt)
#pragma unroll
      for (int qn = 0; qn < 2; ++qn) st[mt][qn] = (f32x4){0.f, 0.f, 0.f, 0.f};
    __builtin_amdgcn_s_setprio(1);
#pragma unroll
    for (int mt = 0; mt < 4; ++mt) {
      f16x8 ka0 = *(const f16x8*)(Kc + (mt * 16 + l15) * 72 + quad * 8);
      f16x8 ka1 = *(const f16x8*)(Kc + (mt * 16 + l15) * 72 + 32 + quad * 8);
#pragma unroll
      for (int qn = 0; qn < 2; ++qn) {
        st[mt][qn] = MFMA16(ka0, qf[qn][0], st[mt][qn]);
        st[mt][qn] = MFMA16(ka1, qf[qn][1], st[mt][qn]);
      }
    }
    __builtin_amdgcn_s_setprio(0);
    // exp2 (no max subtraction) + mask-LUT multiply + store P
#pragma unroll
    for (int qn = 0; qn < 2; ++qn)
#pragma unroll
      for (int mt = 0; mt < 4; ++mt) {
        float e0 = EXP2(fminf(st[mt][qn][0], 15.f));
        float e1 = EXP2(fminf(st[mt][qn][1], 15.f));
        float e2 = EXP2(fminf(st[mt][qn][2], 15.f));
        float e3 = EXP2(fminf(st[mt][qn][3], 15.f));
        h16x2 lo = __builtin_amdgcn_cvt_pkrtz(e0, e1);
        h16x2 hi = __builtin_amdgcn_cvt_pkrtz(e2, e3);
        f16x4 pk;
        pk[0] = (_Float16)lo[0]; pk[1] = (_Float16)lo[1];
        pk[2] = (_Float16)hi[0]; pk[3] = (_Float16)hi[1];
        const unsigned nib = (unsigned)(mc[qn] >> (mt * 16 + quad * 4)) & 15u;
        pk *= *(const f16x4*)LUT[nib];
        *(f16x4*)(&Ps[w][(qn * 16 + l15) * 72 + mt * 16 + quad * 4]) = pk;
      }
    // O += P V ; l += P·1  (wave-private P; V frags shared across q-frags)
    f16x8 pa[2][2];
#pragma unroll
    for (int qn = 0; qn < 2; ++qn) {
      pa[qn][0] = *(const f16x8*)(&Ps[w][(qn * 16 + l15) * 72 + quad * 8]);
      pa[qn][1] = *(const f16x8*)(&Ps[w][(qn * 16 + l15) * 72 + 32 + quad * 8]);
      lacc[qn] = MFMA16(pa[qn][0], ones, lacc[qn]);
      lacc[qn] = MFMA16(pa[qn][1], ones, lacc[qn]);
    }
    __builtin_amdgcn_s_setprio(1);
#pragma unroll
    for (int dt = 0; dt < 4; ++dt) {
      f16x8 vb0 = *(const f16x8*)(Vc + (dt * 16 + l15) * 72 + quad * 8);
      f16x8 vb1 = *(const f16x8*)(Vc + (dt * 16 + l15) * 72 + 32 + quad * 8);
#pragma unroll
      for (int qn = 0; qn < 2; ++qn) {
        o_[qn][dt] = MFMA16(pa[qn][0], vb0, o_[qn][dt]);
        o_[qn][dt] = MFMA16(pa[qn][1], vb1, o_[qn][dt]);
      }
    }
    __builtin_amdgcn_s_setprio(0);
    __syncthreads();  // tile kt+1 writes visible; buf cur free for kt+2 writes
  }
  // normalize + write: lacc rows align with o_ rows -> no shuffles
#pragma unroll
  for (int qn = 0; qn < 2; ++qn) {
    f32x4 inv;
#pragma unroll
    for (int r = 0; r < 4; ++r) inv[r] = 1.f / lacc[qn][r];
#pragma unroll
    for (int dt = 0; dt < 4; ++dt)
#pragma unroll
      for (int r = 0; r < 4; ++r)
        vals[(size_t)(b * SEQ + q0 + w * 32 + qn * 16 + quad * 4 + r) * DM +
             h * HD + dt * 16 + l15] = (_Float16)(o_[qn][dt][r] * inv[r]);
  }
}

extern "C" void kernel_launch(void* const* d_in, const int* in_sizes, int n_in,
                              void* d_out, int out_size, void* d_ws, size_t ws_size,
                              hipStream_t stream) {
  const float* x    = (const float*)d_in[0];
  const int*   mask = (const int*)  d_in[1];
  const float* Wqkv = (const float*)d_in[2];
  const float* bqkv = (const float*)d_in[3];
  const float* Wo   = (const float*)d_in[4];
  const float* bo   = (const float*)d_in[5];
  float* out = (float*)d_out;

  char* ws = (char*)d_ws;
  _Float16* qkv16  = (_Float16*)ws;                    ws += (size_t)BATCH*SEQ*D3*2;   // 24MB (v-cols unused)
  _Float16* vT16   = (_Float16*)ws;                    ws += (size_t)BATCH*DM*SEQ*2;   //  8MB
  _Float16* x16    = (_Float16*)ws;                    ws += (size_t)BATCH*SEQ*DM*2;   //  8MB
  _Float16* WqkvT  = (_Float16*)ws;                    ws += (size_t)DM*D3*2;          //  6MB
  _Float16* WoT    = (_Float16*)ws;                    ws += (size_t)DM*DM*2;          //  2MB
  _Float16* vals16 = (_Float16*)ws;                    ws += (size_t)BATCH*SEQ*DM*2;   //  8MB
  unsigned long long* mbits = (unsigned long long*)ws;                                 // 0.5MB

  // transpose blocks first (they feed the GEMM B operand), then cast, then mask
  prep_all<<<3072 + (BATCH*SEQ*SEQ)/256, 256, 0, stream>>>(
      x, x16, mask, mbits, Wqkv, WqkvT, Wo, WoT);

  gemm_bt<_Float16, true, 128, 64><<<dim3(D3/128, BATCH*SEQ/128), 256, 0, stream>>>(
      x16, WqkvT, bqkv, qkv16, vT16, BATCH*SEQ, D3, DM);
  attn<<<512, 256, 0, stream>>>(qkv16, vT16, mbits, vals16);
  gemm_bt<float, false, 64, 128><<<dim3(DM/64, (BATCH*SEQ)/128), 256, 0, stream>>>(
      vals16, WoT, bo, out, nullptr, BATCH*SEQ, DM, DM);
}